// Round 7
// baseline (589.791 us; speedup 1.0000x reference)
//
#include <hip/hip_runtime.h>
#include <hip/hip_bf16.h>
#include <stdint.h>

typedef __hip_bfloat16 bf16;
typedef __attribute__((ext_vector_type(8))) short short8;   // 8 bf16 = 4 VGPRs (MFMA A/B frag)
typedef __attribute__((ext_vector_type(4))) float f32x4;    // MFMA C/D frag
typedef __attribute__((ext_vector_type(2))) unsigned uint2v;
typedef __attribute__((ext_vector_type(4))) unsigned uint4v;
typedef __attribute__((ext_vector_type(4))) unsigned short ushort4v;

#define B_   4
#define S_   4096
#define D_   1024
#define KSEL 2048
#define DFF  4096
#define NH   16
#define DH   64

// ---------------------------------------------------------------- helpers
static __device__ __forceinline__ void load_lds16(const void* g, void* l) {
  // async global->LDS, 16B per lane, dst = wave-uniform base + lane*16
  __builtin_amdgcn_global_load_lds((const __attribute__((address_space(1))) void*)g,
                                   (__attribute__((address_space(3))) void*)l,
                                   16, 0, 0);
}

static __device__ __forceinline__ short8 scale8(short8 v, float s) {
  short8 r;
#pragma unroll
  for (int i = 0; i < 8; ++i) {
    unsigned u = ((unsigned)(unsigned short)v[i]) << 16;
    float f = __uint_as_float(u) * s;
    bf16 o = __float2bfloat16(f);
    short t;
    __builtin_memcpy(&t, &o, 2);
    r[i] = t;
  }
  return r;
}

static __device__ __forceinline__ unsigned cvt_pk_bf16(float lo, float hi) {
  unsigned r;
  asm("v_cvt_pk_bf16_f32 %0, %1, %2" : "=v"(r) : "v"(lo), "v"(hi));
  return r;
}

static __device__ __forceinline__ void pl32_swap(unsigned &a, unsigned &b) {
#if __has_builtin(__builtin_amdgcn_permlane32_swap)
  uint2v r = __builtin_amdgcn_permlane32_swap(a, b, false, false);
  a = r[0]; b = r[1];
#else
  asm("v_permlane32_swap_b32 %0, %1" : "+v"(a), "+v"(b));
#endif
}

static __device__ __forceinline__ void pl16_swap(unsigned &a, unsigned &b) {
#if __has_builtin(__builtin_amdgcn_permlane16_swap)
  uint2v r = __builtin_amdgcn_permlane16_swap(a, b, false, false);
  a = r[0]; b = r[1];
#else
  asm("v_permlane16_swap_b32 %0, %1" : "+v"(a), "+v"(b));
#endif
}

// ---------------------------------------------------------------- 1) copy x -> out, logits = x @ router_w
__global__ __launch_bounds__(256)
void copy_router(const float* __restrict__ x, const float* __restrict__ rwts,
                 float* __restrict__ out, float* __restrict__ logits)
{
  int s = blockIdx.x, b = blockIdx.y;
  int tid = threadIdx.x;
  const float4* row = (const float4*)(x + ((size_t)b * S_ + s) * D_);
  float4 v = row[tid];
  ((float4*)(out + ((size_t)b * S_ + s) * D_))[tid] = v;
  float4 rv = ((const float4*)rwts)[tid];
  float p = v.x * rv.x + v.y * rv.y + v.z * rv.z + v.w * rv.w;
  for (int off = 32; off; off >>= 1) p += __shfl_down(p, off, 64);
  __shared__ float wsum[4];
  if ((tid & 63) == 0) wsum[tid >> 6] = p;
  __syncthreads();
  if (tid == 0) logits[(size_t)b * S_ + s] = wsum[0] + wsum[1] + wsum[2] + wsum[3];
}

// ---------------------------------------------------------------- 2) per-batch top-K: binary-search threshold select
// T = max u32 key t with count(key >= t) >= KSEL (keys monotone-encoded floats,
// held in registers). Selected set = {key > T} + first (KSEL - n_gt) elements
// with key == T in index order -- identical to stable top_k semantics.
__global__ __launch_bounds__(1024)
void topk_kernel(const float* __restrict__ logits,
                 int* __restrict__ sel, float* __restrict__ rw)
{
  __shared__ int   wredi[16];
  __shared__ float wredf[16];
  __shared__ int   woff[17];

  int b = blockIdx.x, tid = threadIdx.x;
  int lane = tid & 63, wv = tid >> 6;
  const float* L = logits + (size_t)b * S_;
  int base = tid * 4;
  float4 v = ((const float4*)L)[tid];
  // monotone key: ascending key order == ascending float order
  unsigned k0, k1, k2, k3;
  {
    unsigned u;
    u = __float_as_uint(v.x); k0 = (u & 0x80000000u) ? ~u : (u | 0x80000000u);
    u = __float_as_uint(v.y); k1 = (u & 0x80000000u) ? ~u : (u | 0x80000000u);
    u = __float_as_uint(v.z); k2 = (u & 0x80000000u) ? ~u : (u | 0x80000000u);
    u = __float_as_uint(v.w); k3 = (u & 0x80000000u) ? ~u : (u | 0x80000000u);
  }
  // block max (softmax shift; max logit value == max selected value)
  float mx = fmaxf(fmaxf(v.x, v.y), fmaxf(v.z, v.w));
  for (int off = 32; off; off >>= 1) mx = fmaxf(mx, __shfl_xor(mx, off, 64));
  if (lane == 0) wredf[wv] = mx;
  __syncthreads();
  float m = wredf[0];
  for (int w = 1; w < 16; ++w) m = fmaxf(m, wredf[w]);

  // greedy bit-by-bit threshold search (count_ge monotone non-increasing)
  unsigned T = 0;
  for (int bit = 31; bit >= 0; --bit) {
    unsigned cand = T | (1u << bit);
    int c = (int)(k0 >= cand) + (int)(k1 >= cand) + (int)(k2 >= cand) + (int)(k3 >= cand);
    for (int off = 32; off; off >>= 1) c += __shfl_xor(c, off, 64);
    __syncthreads();
    if (lane == 0) wredi[wv] = c;
    __syncthreads();
    int tot = 0;
    for (int w = 0; w < 16; ++w) tot += wredi[w];
    if (tot >= KSEL) T = cand;
  }
  // strictly-greater count
  int cg = (int)(k0 > T) + (int)(k1 > T) + (int)(k2 > T) + (int)(k3 > T);
  for (int off = 32; off; off >>= 1) cg += __shfl_xor(cg, off, 64);
  __syncthreads();
  if (lane == 0) wredi[wv] = cg;
  __syncthreads();
  int n_gt = 0;
  for (int w = 0; w < 16; ++w) n_gt += wredi[w];
  int need = KSEL - n_gt;
  // exclusive prefix of eq-flags (index order) to rank tie elements
  int e0 = (k0 == T), e1 = (k1 == T), e2 = (k2 == T), e3 = (k3 == T);
  int esum = e0 + e1 + e2 + e3;
  int eincl = esum;
  for (int off = 1; off < 64; off <<= 1) { int t = __shfl_up(eincl, off, 64); if (lane >= off) eincl += t; }
  __syncthreads();
  if (lane == 63) wredi[wv] = eincl;
  __syncthreads();
  int ebase = 0;
  for (int w = 0; w < wv; ++w) ebase += wredi[w];
  int ep = ebase + eincl - esum;
  int f0 = (k0 > T) || (e0 && ep < need); ep += e0;
  int f1 = (k1 > T) || (e1 && ep < need); ep += e1;
  int f2 = (k2 > T) || (e2 && ep < need); ep += e2;
  int f3 = (k3 > T) || (e3 && ep < need); ep += e3;
  // softmax denominator over selected
  float part = 0.f;
  if (f0) part += __expf(v.x - m);
  if (f1) part += __expf(v.y - m);
  if (f2) part += __expf(v.z - m);
  if (f3) part += __expf(v.w - m);
  for (int off = 32; off; off >>= 1) part += __shfl_xor(part, off, 64);
  __syncthreads();
  if (lane == 0) wredf[wv] = part;
  __syncthreads();
  float tot = 0.f;
  for (int w = 0; w < 16; ++w) tot += wredf[w];
  float inv = 1.0f / tot;
  // compaction: ascending-index positions via prefix scan
  int mysum = f0 + f1 + f2 + f3;
  int incl = mysum;
  for (int off = 1; off < 64; off <<= 1) { int t = __shfl_up(incl, off, 64); if (lane >= off) incl += t; }
  __syncthreads();
  if (lane == 63) wredi[wv] = incl;
  __syncthreads();
  if (tid == 0) { int s = 0; for (int w = 0; w < 16; ++w) { woff[w] = s; s += wredi[w]; } woff[16] = s; }
  __syncthreads();
  int p = woff[wv] + incl - mysum;
  float vv[4] = { v.x, v.y, v.z, v.w };
  int ff[4] = { f0, f1, f2, f3 };
  for (int q = 0; q < 4; ++q) {
    if (ff[q]) {
      sel[b * KSEL + p] = base + q;
      rw[b * KSEL + p] = __expf(vv[q] - m) * inv;
      p++;
    }
  }
}

// ---------------------------------------------------------------- 3) LayerNorm (optional gather) -> bf16
__global__ __launch_bounds__(256)
void ln_kernel(const float* __restrict__ in, const float* __restrict__ x,
               const int* __restrict__ sel,
               const float* __restrict__ g, const float* __restrict__ beta,
               bf16* __restrict__ out, int gather)
{
  int r = blockIdx.x;
  int tid = threadIdx.x;
  const float* src;
  if (gather) {
    int b = r >> 11, t = r & 2047;
    src = x + ((size_t)b * S_ + sel[b * KSEL + t]) * D_;
  } else {
    src = in + (size_t)r * D_;
  }
  float4 v = ((const float4*)src)[tid];
  float s = v.x + v.y + v.z + v.w;
  float sq = v.x * v.x + v.y * v.y + v.z * v.z + v.w * v.w;
  for (int off = 32; off; off >>= 1) { s += __shfl_down(s, off, 64); sq += __shfl_down(sq, off, 64); }
  __shared__ float wsA[4], wsB[4];
  if ((tid & 63) == 0) { wsA[tid >> 6] = s; wsB[tid >> 6] = sq; }
  __syncthreads();
  float stot = wsA[0] + wsA[1] + wsA[2] + wsA[3];
  float sqt  = wsB[0] + wsB[1] + wsB[2] + wsB[3];
  float mean = stot * (1.f / 1024.f);
  float var  = sqt * (1.f / 1024.f) - mean * mean;
  float rs = rsqrtf(var + 1e-5f);
  float4 gv = ((const float4*)g)[tid];
  float4 bv = ((const float4*)beta)[tid];
  bf16* o = out + (size_t)r * D_ + tid * 4;
  o[0] = __float2bfloat16((v.x - mean) * rs * gv.x + bv.x);
  o[1] = __float2bfloat16((v.y - mean) * rs * gv.y + bv.y);
  o[2] = __float2bfloat16((v.z - mean) * rs * gv.z + bv.z);
  o[3] = __float2bfloat16((v.w - mean) * rs * gv.w + bv.w);
}

// ---------------------------------------------------------------- 4) weight cast+transpose fp32[K][N] -> bf16[N][K]
__global__ __launch_bounds__(256)
void wtrans(const float* __restrict__ in, bf16* __restrict__ out, int K, int N)
{
  __shared__ float tile[32][33];
  int n0 = blockIdx.x * 32, k0 = blockIdx.y * 32;
  int r = threadIdx.x >> 5, c = threadIdx.x & 31;
#pragma unroll
  for (int i = 0; i < 4; ++i)
    tile[r + 8 * i][c] = in[(size_t)(k0 + r + 8 * i) * N + n0 + c];
  __syncthreads();
#pragma unroll
  for (int i = 0; i < 4; ++i)
    out[(size_t)(n0 + r + 8 * i) * K + k0 + c] = __float2bfloat16(tile[c][r + 8 * i]);
}

// ---------------------------------------------------------------- 5) V transpose: qkv[t][2048+h*64+d] -> vt[bh][d][t]
__global__ __launch_bounds__(256)
void vt_transpose(const bf16* __restrict__ qkv, bf16* __restrict__ vt)
{
  __shared__ bf16 tile[32][33];
  int bh = blockIdx.z;
  int d0 = blockIdx.y * 32;
  int t0 = blockIdx.x * 32;
  int b = bh >> 4, h = bh & 15;
  int r = threadIdx.x >> 5, c = threadIdx.x & 31;
#pragma unroll
  for (int i = 0; i < 4; ++i) {
    int t = t0 + r + 8 * i;
    tile[r + 8 * i][c] = qkv[(size_t)(b * KSEL + t) * 3072 + 2048 + h * 64 + d0 + c];
  }
  __syncthreads();
#pragma unroll
  for (int i = 0; i < 4; ++i) {
    int d = d0 + r + 8 * i;
    vt[((size_t)bh * 64 + d) * KSEL + t0 + c] = tile[c][r + 8 * i];
  }
}

// ---------------------------------------------------------------- 6) GEMM C = A(bf16 MxK) * Bt(bf16 NxK)^T  + fused epilogues
// XCD-aware remap: xcd = w&7 owns bm-range [xcd*GX/8, (xcd+1)*GX/8); the GY
// blocks sharing an A-panel are CONSECUTIVE slots on ONE XCD -> each A k-slice
// is fetched into that XCD's L2 once (was: once per column-block via L3).
// B k-slices: GY panels x 16KB per k-step, L2-resident. Pure bijection --
// correctness independent of the dispatch model (G16).
// EPI 0: store bf16            (QKV)
// EPI 1: Cf = gather(x) + acc  (o-proj residual, fp32)
// EPI 2: store bf16 gelu(acc)  (FFN1)
// EPI 3: out[b,sel,n] += rw*(x1 + acc)  (FFN2 + final scatter; each (gm,gn)
//        owned by exactly one thread -- sel entries distinct -- plain RMW)
template<int EPI, int TN>
__global__ __launch_bounds__(256)
void gemm_bt(const bf16* __restrict__ A, const bf16* __restrict__ Bt,
             float* __restrict__ Cf, bf16* __restrict__ Cb,
             int M, int N, int K,
             const float* __restrict__ xin, const int* __restrict__ sel,
             const float* __restrict__ rw, const float* __restrict__ x1,
             float* __restrict__ outp)
{
  constexpr int NT = TN / 32;
  constexpr int WN = TN / 2;
  __shared__ bf16 As[128 * 64];
  __shared__ bf16 Bs[TN * 64];
  const int tid = threadIdx.x;
  const int wid = tid >> 6;
  const int lane = tid & 63;
  const int l15 = lane & 15;
  const int quad = lane >> 4;
  const int wm = wid >> 1, wn = wid & 1;

  // XCD-aware panel-ownership remap (GX % 8 == 0, nwg % 8 == 0 for all uses)
  const int GX = gridDim.x, GY = gridDim.y;
  const int w = blockIdx.x + GX * blockIdx.y;
  const int xcd = w & 7, slot = w >> 3;
  const int bm = (xcd * (GX >> 3) + slot / GY) * 128;
  const int bn = (slot % GY) * TN;

  const int srow = lane >> 3;
  const int sgrp = (lane & 7) ^ srow;

  f32x4 acc[4][NT] = {};

  for (int k0 = 0; k0 < K; k0 += 64) {
#pragma unroll
    for (int c2 = 0; c2 < 4; ++c2) {
      int c = wid * 4 + c2;
      const bf16* ga = A + (size_t)(bm + c * 8 + srow) * K + (k0 + sgrp * 8);
      load_lds16(ga, &As[c * 512]);
    }
#pragma unroll
    for (int c2 = 0; c2 < TN / 32; ++c2) {
      int c = wid * (TN / 32) + c2;
      const bf16* gb = Bt + (size_t)(bn + c * 8 + srow) * K + (k0 + sgrp * 8);
      load_lds16(gb, &Bs[c * 512]);
    }
    __syncthreads();
#pragma unroll
    for (int ks = 0; ks < 2; ++ks) {
      short8 af[4], bfv[NT];
#pragma unroll
      for (int mt = 0; mt < 4; ++mt) {
        int row = wm * 64 + mt * 16 + l15;
        int cg = (ks * 4 + quad) ^ (row & 7);
        af[mt] = *(const short8*)&As[row * 64 + cg * 8];
      }
#pragma unroll
      for (int nt = 0; nt < NT; ++nt) {
        int row = wn * WN + nt * 16 + l15;
        int cg = (ks * 4 + quad) ^ (row & 7);
        bfv[nt] = *(const short8*)&Bs[row * 64 + cg * 8];
      }
#pragma unroll
      for (int mt = 0; mt < 4; ++mt)
#pragma unroll
        for (int nt = 0; nt < NT; ++nt)
          acc[mt][nt] = __builtin_amdgcn_mfma_f32_16x16x32_bf16(af[mt], bfv[nt], acc[mt][nt], 0, 0, 0);
    }
    __syncthreads();
  }

#pragma unroll
  for (int mt = 0; mt < 4; ++mt) {
#pragma unroll
    for (int r = 0; r < 4; ++r) {
      int gm = bm + wm * 64 + mt * 16 + quad * 4 + r;
      int bb = gm >> 11, tt = gm & 2047;
      int sr = 0; float rwv = 0.f;
      if (EPI == 1 || EPI == 3) sr = sel[bb * KSEL + tt];
      if (EPI == 3) rwv = rw[bb * KSEL + tt];
#pragma unroll
      for (int nt = 0; nt < NT; ++nt) {
        int gn = bn + wn * WN + nt * 16 + l15;
        float v = acc[mt][nt][r];
        if (EPI == 0) {
          Cb[(size_t)gm * N + gn] = __float2bfloat16(v);
        } else if (EPI == 1) {
          float xv = xin[((size_t)bb * S_ + sr) * D_ + gn];
          Cf[(size_t)gm * N + gn] = xv + v;
        } else if (EPI == 2) {
          float u = v;
          float cc = 0.7978845608028654f * (u + 0.044715f * u * u * u);
          float e = __expf(2.f * cc);
          float th = 1.f - 2.f / (e + 1.f);
          Cb[(size_t)gm * N + gn] = __float2bfloat16(0.5f * u * (1.f + th));
        } else {
          float v2 = rwv * (x1[(size_t)gm * D_ + gn] + v);
          outp[((size_t)bb * S_ + sr) * D_ + gn] += v2;
        }
      }
    }
  }
}

// ---------------------------------------------------------------- 7) flash attention, swapped-operand + in-register P
// Single-buffer staging (cross-block TLP hides the drain -- R4 post-mortem).
// l-via-MFMA (R5). XCD-aware remap: all 16 qt-blocks of one (b,h) land on one
// XCD -> its K/V panels (512 KB) are fetched into that L2 once, not 16x.
__global__ __launch_bounds__(256)
void flash_kernel(const bf16* __restrict__ qkv, const bf16* __restrict__ vt,
                  bf16* __restrict__ attn_o)
{
  __shared__ bf16 Ks[128 * 64];        // [token][dh]   16 KB
  __shared__ bf16 Vs[64 * 128];        // [dh][token]   16 KB
  // grid (16, NH, B_) -> linear w, then: xcd owns 8 (b,h) groups x 16 qt
  int w = blockIdx.x + 16 * (blockIdx.y + NH * blockIdx.z);
  int xcd = w & 7, slot = w >> 3;
  int bh = xcd * 8 + (slot >> 4);
  int qt = slot & 15;
  int h = bh & 15, b = bh >> 4;
  int tid = threadIdx.x, wid = tid >> 6, lane = tid & 63;
  int l15 = lane & 15, quad = lane >> 4;
  int q0 = qt * 128 + wid * 32;

  const int srowK = lane >> 3, sgK = lane & 7;
  const int srowV = lane >> 4, sgV = lane & 15;

  short8 qf[2][2];
#pragma unroll
  for (int mt = 0; mt < 2; ++mt)
#pragma unroll
    for (int ks = 0; ks < 2; ++ks) {
      const bf16* p = qkv + (size_t)(b * KSEL + q0 + mt * 16 + l15) * 3072 + h * 64 + ks * 32 + quad * 8;
      qf[mt][ks] = scale8(*(const short8*)p, 0.125f * 1.44269504f);
    }

  short8 ones8;
  {
    short o1 = (short)0x3F80;   // bf16 1.0
#pragma unroll
    for (int i = 0; i < 8; ++i) ones8[i] = o1;
  }

  f32x4 acc_ot[2][4] = {};   // O^T: lane holds O^T[dh=dt*16+quad*4+r][q=mt*16+l15]
  f32x4 acc_l[2] = {};       // l:   every row identical; l(q=l15) = acc_l[mt][0]

  const bf16* Vg = vt + (size_t)(b * NH + h) * 64 * KSEL;

  for (int kt = 0; kt < KSEL / 128; ++kt) {
    int tok0 = b * KSEL + kt * 128;
    __syncthreads();   // previous tile's LDS reads complete
#pragma unroll
    for (int i = 0; i < 4; ++i) {
      int c = wid * 4 + i;
      const bf16* ga = qkv + (size_t)(tok0 + c * 8 + srowK) * 3072 + 1024 + h * 64 + ((sgK ^ srowK) * 8);
      load_lds16(ga, &Ks[c * 512]);
      int vr = c * 4 + srowV;
      const bf16* gv = Vg + (size_t)vr * KSEL + kt * 128 + ((sgV ^ (vr & 7)) * 8);
      load_lds16(gv, &Vs[c * 512]);
    }
    __syncthreads();   // staging drained (vmcnt(0) before s_barrier)

#pragma unroll
    for (int ks4 = 0; ks4 < 4; ++ks4) {
      // ---- QK^T (swapped): S^T tiles for the two 16-token groups of this 32-k block
      f32x4 s[2][2] = {};
#pragma unroll
      for (int u = 0; u < 2; ++u) {
        int row = (ks4 * 2 + u) * 16 + l15;
#pragma unroll
        for (int ks = 0; ks < 2; ++ks) {
          int g = (ks * 4 + quad) ^ (row & 7);
          short8 kf = *(const short8*)&Ks[row * 64 + g * 8];
#pragma unroll
          for (int mt = 0; mt < 2; ++mt)
            s[mt][u] = __builtin_amdgcn_mfma_f32_16x16x32_bf16(kf, qf[mt][ks], s[mt][u], 0, 0, 0);
        }
      }
      // ---- softmax + in-register transpose into P^T B-fragments
      short8 pfrag[2];
#pragma unroll
      for (int mt = 0; mt < 2; ++mt) {
        float pA[4], pB[4];
#pragma unroll
        for (int r = 0; r < 4; ++r) {
          pA[r] = __builtin_amdgcn_exp2f(s[mt][0][r]);
          pB[r] = __builtin_amdgcn_exp2f(s[mt][1][r]);
        }
        unsigned A0 = cvt_pk_bf16(pA[0], pA[1]);
        unsigned A1 = cvt_pk_bf16(pA[2], pA[3]);
        unsigned B0 = cvt_pk_bf16(pB[0], pB[1]);
        unsigned B1 = cvt_pk_bf16(pB[2], pB[3]);
        pl32_swap(A0, B0); pl16_swap(A0, B0);
        pl32_swap(A1, B1); pl16_swap(A1, B1);
        uint4v w4; w4[0] = A0; w4[1] = A1; w4[2] = B0; w4[3] = B1;
        pfrag[mt] = __builtin_bit_cast(short8, w4);
        // l partial for this 32-k block via MFMA (full cross-quad k-sum)
        acc_l[mt] = __builtin_amdgcn_mfma_f32_16x16x32_bf16(ones8, pfrag[mt], acc_l[mt], 0, 0, 0);
      }
      // ---- PV (transposed): O^T += V^T[:, k-block] * P^T[k-block, :]
#pragma unroll
      for (int dt = 0; dt < 4; ++dt) {
        int row = dt * 16 + l15;
        int g = (ks4 * 4 + quad) ^ (row & 7);
        short8 vf = *(const short8*)&Vs[row * 128 + g * 8];
#pragma unroll
        for (int mt = 0; mt < 2; ++mt)
          acc_ot[mt][dt] = __builtin_amdgcn_mfma_f32_16x16x32_bf16(vf, pfrag[mt], acc_ot[mt][dt], 0, 0, 0);
      }
    }
  }
#pragma unroll
  for (int mt = 0; mt < 2; ++mt) {
    float invl = 1.0f / acc_l[mt][0];
#pragma unroll
    for (int dt = 0; dt < 4; ++dt) {
      ushort4v o;
#pragma unroll
      for (int r = 0; r < 4; ++r) {
        bf16 t = __float2bfloat16(acc_ot[mt][dt][r] * invl);
        unsigned short us;
        __builtin_memcpy(&us, &t, 2);
        o[r] = us;
      }
      *(ushort4v*)(attn_o + (size_t)(b * KSEL + q0 + mt * 16 + l15) * D_ + h * 64 + dt * 16 + quad * 4) = o;
    }
  }
}

// ---------------------------------------------------------------- launch
extern "C" void kernel_launch(void* const* d_in, const int* in_sizes, int n_in,
                              void* d_out, int out_size, void* d_ws, size_t ws_size,
                              hipStream_t stream)
{
  const float* x      = (const float*)d_in[0];
  const float* router = (const float*)d_in[1];
  const float* ln1g   = (const float*)d_in[2];
  const float* ln1b   = (const float*)d_in[3];
  const float* ln2g   = (const float*)d_in[4];
  const float* ln2b   = (const float*)d_in[5];
  const float* wqkv   = (const float*)d_in[6];
  const float* wo     = (const float*)d_in[7];
  const float* w1     = (const float*)d_in[8];
  const float* w2     = (const float*)d_in[9];
  float* out = (float*)d_out;
  char* ws = (char*)d_ws;

  float* logits = (float*)(ws + 0);                 // 64 KB
  int*   sel    = (int*)  (ws + 65536);             // 32 KB
  float* rw     = (float*)(ws + 98304);             // 32 KB
  bf16* wqkvT   = (bf16*) (ws + 131072);            // 6 MB   [3072][1024]
  bf16* woT     = (bf16*) (ws + 6422528);           // 2 MB   [1024][1024]
  bf16* w1T     = (bf16*) (ws + 8519680);           // 8 MB   [4096][1024]
  bf16* w2T     = (bf16*) (ws + 16908288);          // 8 MB   [1024][4096]
  bf16* regA    = (bf16*) (ws + 25296896);          // 16 MB  h1 / attn_o / h2
  bf16* regB    = (bf16*) (ws + 42074112);          // 64 MB  qkv(48)+vt(16) then ffn_h
  bf16* vtb     = (bf16*) (ws + 42074112 + 50331648);
  float* x1     = (float*)(ws + 109182976);         // 32 MB

  copy_router<<<dim3(S_, B_), 256, 0, stream>>>(x, router, out, logits);
  topk_kernel<<<B_, 1024, 0, stream>>>(logits, sel, rw);

  wtrans<<<dim3(3072 / 32, 1024 / 32), 256, 0, stream>>>(wqkv, wqkvT, 1024, 3072);
  wtrans<<<dim3(1024 / 32, 1024 / 32), 256, 0, stream>>>(wo,   woT,   1024, 1024);
  wtrans<<<dim3(4096 / 32, 1024 / 32), 256, 0, stream>>>(w1,   w1T,   1024, 4096);
  wtrans<<<dim3(1024 / 32, 4096 / 32), 256, 0, stream>>>(w2,   w2T,   4096, 1024);

  ln_kernel<<<B_ * KSEL, 256, 0, stream>>>(nullptr, x, sel, ln1g, ln1b, regA, 1);

  // QKV: [8192x1024] * [3072x1024]^T -> bf16 [8192][3072]
  gemm_bt<0, 128><<<dim3(64, 24), 256, 0, stream>>>(regA, wqkvT, nullptr, regB, 8192, 3072, 1024,
                                                    nullptr, nullptr, nullptr, nullptr, nullptr);
  vt_transpose<<<dim3(KSEL / 32, 2, B_ * NH), 256, 0, stream>>>(regB, vtb);
  flash_kernel<<<dim3(KSEL / 128, NH, B_), 256, 0, stream>>>(regB, vtb, regA);

  // o-proj + gather residual: x1 = gather(x) + attn_o * wo
  gemm_bt<1, 128><<<dim3(64, 8), 256, 0, stream>>>(regA, woT, x1, nullptr, 8192, 1024, 1024,
                                                   x, sel, nullptr, nullptr, nullptr);
  ln_kernel<<<B_ * KSEL, 256, 0, stream>>>(x1, nullptr, nullptr, ln2g, ln2b, regA, 0);
  // FFN1 + gelu -> bf16 [8192][4096]
  gemm_bt<2, 128><<<dim3(64, 32), 256, 0, stream>>>(regA, w1T, nullptr, regB, 8192, 4096, 1024,
                                                    nullptr, nullptr, nullptr, nullptr, nullptr);
  // FFN2 + scatter: out[b,sel,:] += rw * (x1 + acc)
  gemm_bt<3, 128><<<dim3(64, 8), 256, 0, stream>>>(regB, w2T, nullptr, nullptr, 8192, 1024, 4096,
                                                   nullptr, sel, rw, x1, out);
}